// Round 9
// baseline (391.876 us; speedup 1.0000x reference)
//
#include <hip/hip_runtime.h>

// Butterfly multiply, B=16384, N=2048, LOG_N=11, increasing stride.
//
// R13: RESIDENCY is the binding resource. Clean structure points:
//   R0  ROWS=2  88 regs  5 waves/SIMD  145us  VALUBusy 31%
//   R11 ROWS=2 224 regs  2 waves/SIMD  190us  VALUBusy 25%  (LDS pipeline)
//   R12 ROWS=4 256 regs  2 waves/SIMD  171us  VALUBusy 14%
// VALUBusy ~ linear in resident waves; duration anti-correlates with
// per-wave fatness. Latency-bound: maximize waves/SIMD.
//   - ROWS=1: v[32]=32 data regs + ~30 overhead -> ~64 VGPR -> 8 waves/SIMD
//     (1.6x R0). Twiddle amortization lost, but stage tables (16 KiB) are
//     L1-resident and extra waves hide the gather latency.
//   - 4-els-per-lane layout e = r*256 + lane*4 + jj (r<8, jj<4):
//     x/out/bias I/O = perfect 1-KiB float4 transactions (half the instrs);
//     stages 0-1 in-lane, 2-7 cross-lane (masks 1..32), 8-10 in-register.
//   - cm/cp shared selects (R12, verified); DPP for masks 1,2; ds_swizzle
//     4,8,16; shfl_xor 32.
//   - launch_bounds(256,2): 128-reg budget; pressure ~70 -> no spill
//     (R0 proof: compiler uses true pressure when it fits the budget).
// CRITICAL (R4 lesson): every loop fully unrolled; all v[] indices
// compile-time, else scratch allocation.

constexpr int BATCH = 16384;
constexpr int N = 2048;
constexpr int WPB = 4;              // waves per block; 1 row per wave
constexpr int BLOCK = 64 * WPB;     // 256 threads
constexpr int GRID = BATCH / WPB;   // 4096 blocks

// Bounds twiddle-load hoisting (register pressure), costs no instructions.
#define SCHED_FENCE() asm volatile("" ::: "memory")

// Cross-lane partner (lane ^ M), cheapest pipe per mask.
template <int M>
__device__ __forceinline__ float part_xor(float x) {
    if constexpr (M == 1)        // quad_perm [1,0,3,2]
        return __int_as_float(__builtin_amdgcn_mov_dpp(__float_as_int(x), 0xB1, 0xF, 0xF, true));
    else if constexpr (M == 2)   // quad_perm [2,3,0,1]
        return __int_as_float(__builtin_amdgcn_mov_dpp(__float_as_int(x), 0x4E, 0xF, 0xF, true));
    else if constexpr (M == 4)   // xor 4 within 32-half
        return __int_as_float(__builtin_amdgcn_ds_swizzle(__float_as_int(x), 0x101F));
    else if constexpr (M == 8)
        return __int_as_float(__builtin_amdgcn_ds_swizzle(__float_as_int(x), 0x201F));
    else if constexpr (M == 16)
        return __int_as_float(__builtin_amdgcn_ds_swizzle(__float_as_int(x), 0x401F));
    else
        return __shfl_xor(x, 32, 64);
}

// stages 2..7 (s=4..128): pair bit st = lane bit (st-2) -> cross-lane.
// cm = coeff of my value, cp = coeff of partner (verified R12, passed):
//   h=0: out = t2.x*mine + t2.y*part ; h=1: out = t2.y*mine + t2.x*part
template <int ST>
__device__ __forceinline__ void mid_stage(float (&v)[32], const float* twst, int lane) {
    constexpr int s = 1 << ST;
    constexpr int m = 1 << (ST - 2);
    const int h = (lane >> (ST - 2)) & 1;
    const int l4 = lane * 4;
    #pragma unroll
    for (int k = 0; k < 32; ++k) {
        const int e = (k >> 2) * 256 + l4 + (k & 3);
        const int p = ((e >> (ST + 1)) << ST) | (e & (s - 1));
        const float2 t2 = *(const float2*)(twst + 4 * p + 2 * h);
        const float cm = h ? t2.y : t2.x;
        const float cp = h ? t2.x : t2.y;
        const float part = part_xor<m>(v[k]);
        v[k] = fmaf(cm, v[k], cp * part);
        if ((k & 3) == 3) SCHED_FENCE();   // bound in-flight float2 at ~4
    }
}

// stages 8..10 (s=256..1024): pair bit st = r bit (st-8) -> in-register.
template <int ST>
__device__ __forceinline__ void hi_stage(float (&v)[32], const float* twst, int lane) {
    constexpr int s = 1 << ST;
    constexpr int rm = 1 << (ST - 8);
    const int l4 = lane * 4;
    #pragma unroll
    for (int r = 0; r < 8; ++r) {
        if (r & rm) continue;              // visit each pair at lo (compile-time)
        #pragma unroll
        for (int jj = 0; jj < 4; ++jj) {
            const int e = r * 256 + l4 + jj;
            const int p = ((e >> (ST + 1)) << ST) | (e & (s - 1));
            const float4 t4 = *(const float4*)(twst + 4 * p);
            const int klo = 4 * r + jj;
            const int khi = 4 * (r + rm) + jj;
            const float lo = v[klo];
            const float hi = v[khi];
            v[klo] = fmaf(t4.x, lo, t4.y * hi);
            v[khi] = fmaf(t4.z, lo, t4.w * hi);
            if ((jj & 1) == 1) SCHED_FENCE();  // bound in-flight float4 at ~2
        }
    }
}

__global__ __launch_bounds__(BLOCK, 2)
void butterfly_kernel(const float* __restrict__ x,
                      const float* __restrict__ tw,
                      const float* __restrict__ bias,
                      float* __restrict__ out)
{
    const int tid = threadIdx.x;
    const int lane = tid & 63;
    const int w = tid >> 6;
    const size_t row = (size_t)blockIdx.x * WPB + w;
    const int l4 = lane * 4;

    float v[32];

    // ---- x load: 8 perfectly-coalesced float4 (1 KiB per wave-inst)
    const float* src = x + row * N + l4;
    #pragma unroll
    for (int r = 0; r < 8; ++r) {
        const float4 f = *(const float4*)(src + r * 256);
        v[4*r]   = f.x;
        v[4*r+1] = f.y;
        v[4*r+2] = f.z;
        v[4*r+3] = f.w;
    }

    // ---- stage 0 (s=1): in-lane pair = jj bit 0.
    // e_lo = r*256 + lane*4 + 2*jh  ->  p = e_lo>>1 = r*128 + lane*2 + jh
    #pragma unroll
    for (int r = 0; r < 8; ++r) {
        #pragma unroll
        for (int jh = 0; jh < 2; ++jh) {
            const int p = r * 128 + lane * 2 + jh;
            const float4 t4 = *(const float4*)(tw + 4 * p);
            const int klo = 4 * r + 2 * jh;
            const float lo = v[klo];
            const float hi = v[klo + 1];
            v[klo]     = fmaf(t4.x, lo, t4.y * hi);
            v[klo + 1] = fmaf(t4.z, lo, t4.w * hi);
        }
        if (r & 1) SCHED_FENCE();
    }

    // ---- stage 1 (s=2): in-lane pair = jj bit 1.
    // e_lo = r*256 + lane*4 + jl  ->  p = ((e>>2)<<1)|(e&1) = r*128 + lane*2 + jl
    {
        const float* tw1 = tw + 4096;
        #pragma unroll
        for (int r = 0; r < 8; ++r) {
            #pragma unroll
            for (int jl = 0; jl < 2; ++jl) {
                const int p = r * 128 + lane * 2 + jl;
                const float4 t4 = *(const float4*)(tw1 + 4 * p);
                const int klo = 4 * r + jl;
                const float lo = v[klo];
                const float hi = v[klo + 2];
                v[klo]     = fmaf(t4.x, lo, t4.y * hi);
                v[klo + 2] = fmaf(t4.z, lo, t4.w * hi);
            }
            if (r & 1) SCHED_FENCE();
        }
    }

    // ---- stages 2..7: cross-lane (masks 1,2,4,8,16,32), twiddles L2/L1-direct
    mid_stage<2>(v, tw + (2 << 12), lane);
    mid_stage<3>(v, tw + (3 << 12), lane);
    mid_stage<4>(v, tw + (4 << 12), lane);
    mid_stage<5>(v, tw + (5 << 12), lane);
    mid_stage<6>(v, tw + (6 << 12), lane);
    mid_stage<7>(v, tw + (7 << 12), lane);

    // ---- stages 8..10: in-register
    hi_stage<8>(v,  tw + (8 << 12), lane);
    hi_stage<9>(v,  tw + (9 << 12), lane);
    hi_stage<10>(v, tw + (10 << 12), lane);

    // ---- store with bias: 8 coalesced float4
    float* dst = out + row * N + l4;
    #pragma unroll
    for (int r = 0; r < 8; ++r) {
        const float4 b = *(const float4*)(bias + r * 256 + l4);
        float4 o;
        o.x = v[4*r]   + b.x;
        o.y = v[4*r+1] + b.y;
        o.z = v[4*r+2] + b.z;
        o.w = v[4*r+3] + b.w;
        *(float4*)(dst + r * 256) = o;
    }
}

extern "C" void kernel_launch(void* const* d_in, const int* in_sizes, int n_in,
                              void* d_out, int out_size, void* d_ws, size_t ws_size,
                              hipStream_t stream) {
    const float* x    = (const float*)d_in[0];
    const float* tw   = (const float*)d_in[1];
    const float* bias = (const float*)d_in[2];
    float* out = (float*)d_out;

    butterfly_kernel<<<GRID, BLOCK, 0, stream>>>(x, tw, bias, out);
}